// Round 8
// baseline (146.748 us; speedup 1.0000x reference)
//
#include <hip/hip_runtime.h>

// Problem: B=2, C=256, F*H*W=N=4096, heads=4, dim_head=64, inner=256
#define BATCH 2
#define CCH   256
#define NSEQ  4096
#define NH    4
#define DH    64
#define INNER 256

typedef __attribute__((ext_vector_type(8))) __bf16 bf16x8;
typedef __attribute__((ext_vector_type(4))) float f32x4;
typedef __attribute__((ext_vector_type(8))) unsigned short u16x8;
typedef __attribute__((ext_vector_type(4))) unsigned short u16x4;
typedef __attribute__((ext_vector_type(4))) short s16x4;

// async global->LDS, 16B per lane; LDS dest = wave-uniform base + lane*16
#define GLD16(gsrc, ldst)                                                     \
  __builtin_amdgcn_global_load_lds(                                           \
      (const __attribute__((address_space(1))) unsigned int*)(const void*)(gsrc), \
      (__attribute__((address_space(3))) unsigned int*)(void*)(ldst), 16, 0, 0)

// round-half-up bf16 (inputs finite; <=0.5ulp bias vs RNE, irrelevant here)
static __device__ __forceinline__ unsigned short f2bfr(float f) {
  union { float f; unsigned u; } v; v.f = f;
  return (unsigned short)((v.u + 0x8000u) >> 16);
}
// pack two floats -> bf16 pair (low = f0) via v_perm_b32: 3 VALU ops
static __device__ __forceinline__ unsigned pack2(float f0, float f1) {
  union { float f; unsigned u; } a, b; a.f = f0; b.f = f1;
  return __builtin_amdgcn_perm(b.u + 0x8000u, a.u + 0x8000u, 0x07060302u);
}
static __device__ __forceinline__ float bf2f(unsigned short u) {
  union { unsigned u; float f; } v; v.u = ((unsigned)u) << 16;
  return v.f;
}
static __device__ __forceinline__ bf16x8 ldb(const unsigned short* p) {
  return *(const bf16x8*)p;
}
static __device__ __forceinline__ f32x4 mm(bf16x8 a, bf16x8 b, f32x4 c) {
  return __builtin_amdgcn_mfma_f32_16x16x32_bf16(a, b, c, 0, 0, 0);
}
// K=16 bf16 MFMA (gfx90a-lineage "_1k", present on gfx950 per ISA §10)
static __device__ __forceinline__ f32x4 mm16(s16x4 a, s16x4 b, f32x4 c) {
  return __builtin_amdgcn_mfma_f32_16x16x16bf16_1k(a, b, c, 0, 0, 0);
}

// ------ Kernel 1: LN -> xn [b][n][c] bf16  (+ fused fp32->bf16 weight cvt) --
__global__ __launch_bounds__(256) void k_lncvt(const float* __restrict__ x,
                                               const float* __restrict__ gamma,
                                               unsigned short* __restrict__ xn,
                                               const float* __restrict__ wq,
                                               const float* __restrict__ wo,
                                               unsigned short* __restrict__ wqb,
                                               unsigned short* __restrict__ wob) {
  int blk = blockIdx.x;
  if (blk >= 256) {                       // weight convert: 256 blocks
    int t = (blk - 256) * 256 + threadIdx.x;
    int e = t * 4;
    if (e < 768 * 256) {
      float4 v = *(const float4*)(wq + e);
      u16x4 pk = { f2bfr(v.x), f2bfr(v.y), f2bfr(v.z), f2bfr(v.w) };
      *(u16x4*)(wqb + e) = pk;
    } else {
      int e2 = e - 768 * 256;
      float4 v = *(const float4*)(wo + e2);
      u16x4 pk = { f2bfr(v.x), f2bfr(v.y), f2bfr(v.z), f2bfr(v.w) };
      *(u16x4*)(wob + e2) = pk;
    }
    return;
  }
  int b  = blk >> 7;
  int n0 = (blk & 127) * 32;
  int t  = threadIdx.x;
  int nl = t & 31;
  int cg = t >> 5;                 // channel group 0..7 (32 channels each)
  int n  = n0 + nl;
  const float* xp = x + ((size_t)(b * CCH + cg * 32)) * NSEQ + n;
  float vals[32];
  float s = 0.f, s2 = 0.f;
#pragma unroll
  for (int j = 0; j < 32; j++) {
    float v = xp[(size_t)j * NSEQ];
    vals[j] = v; s += v; s2 += v * v;
  }
  __shared__ float rs[8][32], rs2[8][32];
  rs[cg][nl] = s; rs2[cg][nl] = s2;
  __syncthreads();
  float S = 0.f, S2 = 0.f;
#pragma unroll
  for (int g = 0; g < 8; g++) { S += rs[g][nl]; S2 += rs2[g][nl]; }
  float mean = S * (1.f / 256.f);
  float var  = S2 * (1.f / 256.f) - mean * mean;
  float rstd = rsqrtf(var + 1e-5f);
  unsigned short* dst = xn + ((size_t)b * NSEQ + n) * CCH + cg * 32;
#pragma unroll
  for (int j0 = 0; j0 < 32; j0 += 8) {
    u16x8 pk;
#pragma unroll
    for (int j = 0; j < 8; j++)
      pk[j] = f2bfr((vals[j0 + j] - mean) * rstd * gamma[cg * 32 + j0 + j]);
    *(u16x8*)(dst + j0) = pk;
  }
}

// --- Kernel 2: QKV GEMM + fused l2norm, BK=128 (3 barriers total) ----------
// Tiles staged via global_load_lds into stride-128 rows, XOR chunk swizzle.
// oi 0..3: q head oi -> qt (scaled 8*log2e); 4..7: k -> ktb; 8..11: v -> qkv.
__global__ __launch_bounds__(256) void k_qkv(const unsigned short* __restrict__ wqb,
                                             const unsigned short* __restrict__ xn,
                                             unsigned short* __restrict__ qkv,
                                             unsigned short* __restrict__ qt,
                                             unsigned short* __restrict__ ktb) {
  int n0 = blockIdx.x * 64;
  int oi = blockIdx.y;
  int o0 = oi * 64;
  int b  = blockIdx.z;
  __shared__ unsigned short Al[64 * 128];   // [o][k-local] swizzled, 16 KB
  __shared__ unsigned short Bl[64 * 128];   // [n][k-local] swizzled, 16 KB
  int t = threadIdx.x;
  int lane = t & 63, w = t >> 6;
  int c = lane & 15, quad = lane >> 4;
  int wm = w >> 1, wn = w & 1;
  f32x4 acc[2][2] = {};
  int lr = lane >> 4;                       // row within 4-row group
  int lchk = lane & 15;                     // phys chunk (16 chunks/row)
  const unsigned short* apg = wqb + (size_t)o0 * CCH;
  const unsigned short* bpg = xn + ((size_t)b * NSEQ + n0) * CCH;
  for (int kt = 0; kt < 2; kt++) {
    if (kt) __syncthreads();
#pragma unroll
    for (int q = 0; q < 4; q++) {
      int r = w * 16 + q * 4 + lr;
      int srcoff = r * CCH + kt * 128 + ((lchk ^ (r & 7)) * 8);
      GLD16(apg + srcoff, Al + (size_t)(w * 16 + q * 4) * 128);
      GLD16(bpg + srcoff, Bl + (size_t)(w * 16 + q * 4) * 128);
    }
    __syncthreads();
#pragma unroll
    for (int ks = 0; ks < 4; ks++) {
      int ra0 = wm * 32 + c, ra1 = ra0 + 16;
      int rb0 = wn * 32 + c, rb1 = rb0 + 16;
      bf16x8 a0 = ldb(&Al[ra0 * 128 + (((ks * 4 + quad) ^ (ra0 & 7)) * 8)]);
      bf16x8 a1 = ldb(&Al[ra1 * 128 + (((ks * 4 + quad) ^ (ra1 & 7)) * 8)]);
      bf16x8 b0 = ldb(&Bl[rb0 * 128 + (((ks * 4 + quad) ^ (rb0 & 7)) * 8)]);
      bf16x8 b1 = ldb(&Bl[rb1 * 128 + (((ks * 4 + quad) ^ (rb1 & 7)) * 8)]);
      acc[0][0] = mm(a0, b0, acc[0][0]);
      acc[0][1] = mm(a0, b1, acc[0][1]);
      acc[1][0] = mm(a1, b0, acc[1][0]);
      acc[1][1] = mm(a1, b1, acc[1][1]);
    }
  }
  if (oi < 8) {
    // per-n sum of squares: this wave covers d in [wm*32, wm*32+32)
    float* sq = (float*)Al;                 // reuse Al after final reads
    float s0 = 0.f, s1 = 0.f;
#pragma unroll
    for (int i = 0; i < 2; i++)
#pragma unroll
      for (int rr = 0; rr < 4; rr++) {
        s0 += acc[i][0][rr] * acc[i][0][rr];
        s1 += acc[i][1][rr] * acc[i][1][rr];
      }
    s0 += __shfl_xor(s0, 16); s0 += __shfl_xor(s0, 32);
    s1 += __shfl_xor(s1, 16); s1 += __shfl_xor(s1, 32);
    __syncthreads();
    if (quad == 0) {
      sq[wm * 64 + wn * 32 + c]      = s0;
      sq[wm * 64 + wn * 32 + 16 + c] = s1;
    }
    __syncthreads();
    float r0 = rsqrtf(sq[wn * 32 + c]      + sq[64 + wn * 32 + c]      + 1e-12f);
    float r1 = rsqrtf(sq[wn * 32 + 16 + c] + sq[64 + wn * 32 + 16 + c] + 1e-12f);
    if (oi < 4) { r0 *= 11.541560327111707f; r1 *= 11.541560327111707f; } // 8*log2e
    int h = oi & 3;
    unsigned short* base = (oi < 4 ? qt : ktb) + ((size_t)(b * NH + h) * NSEQ) * DH;
#pragma unroll
    for (int i = 0; i < 2; i++)
#pragma unroll
      for (int j = 0; j < 2; j++) {
        float rsc = j ? r1 : r0;
        int n = n0 + wn * 32 + j * 16 + c;
        int d = wm * 32 + i * 16 + quad * 4;
        uint2 pk = { pack2(acc[i][j][0] * rsc, acc[i][j][1] * rsc),
                     pack2(acc[i][j][2] * rsc, acc[i][j][3] * rsc) };
        *(uint2*)(base + (size_t)n * DH + d) = pk;
      }
  } else {
#pragma unroll
    for (int i = 0; i < 2; i++)
#pragma unroll
      for (int j = 0; j < 2; j++)
#pragma unroll
        for (int rr = 0; rr < 4; rr++) {
          int o = o0 + wm * 32 + i * 16 + quad * 4 + rr;
          int n = n0 + wn * 32 + j * 16 + c;
          qkv[((size_t)b * 768 + o) * NSEQ + n] = f2bfr(acc[i][j][rr]);
        }
  }
}

// ------ Kernel 3: flash attention, Q-tile 128, register-P PV ----------------
// Max-free softmax (|sim|<=8 folded as 8*log2e into q), split-KV, dbuf K/V
// (1 barrier/tile). P never touches LDS: exp2(S^T) in C-layout IS the
// B-operand of v_mfma 16x16x16 (k = quad*4+reg), so PV runs as
// O^T[d][i] = V^T[d][j] * P^T[j][i] with V A-frags read b64 from LDS.
__global__ __launch_bounds__(256, 4) void k_attn(
    const unsigned short* __restrict__ qt,
    const unsigned short* __restrict__ ktb,
    const unsigned short* __restrict__ qkv,
    unsigned short* __restrict__ opart,
    float* __restrict__ lpart,
    int S, int kvlen) {
  int i0 = blockIdx.x * 128;
  int h  = blockIdx.y;
  int bz = blockIdx.z;
  int b  = bz / S, s = bz % S;
  __shared__ unsigned short Kl[2][64 * 64];  // [j][d] swizzled, 2x8 KB
  __shared__ unsigned short Vl[2][64 * 64];  // [d][j] swizzled, 2x8 KB
  int t = threadIdx.x;
  int lane = t & 63, w = t >> 6;
  int c = lane & 15, quad = lane >> 4;

  const unsigned short* qbase = qt  + ((size_t)(b * NH + h) * NSEQ) * DH;
  const unsigned short* kbase = ktb + ((size_t)(b * NH + h) * NSEQ) * DH;
  const unsigned short* vbase = qkv + ((size_t)b * 768 + 512 + h * 64) * NSEQ;

  // Q fragments straight from global (one-time, L2-served)
  int rlo = w * 32 + c, rhi = rlo + 16;     // local q-rows of this lane
  const unsigned short* qlo = qbase + (size_t)(i0 + rlo) * DH + quad * 8;
  const unsigned short* qhi = qlo + 16 * DH;
  bf16x8 qlo0 = ldb(qlo), qlo1 = ldb(qlo + 32);
  bf16x8 qhi0 = ldb(qhi), qhi1 = ldb(qhi + 32);

  f32x4 acc[2][4] = {};        // [qset][dt]; acc[q][dt][rr] = O[i=c][d=dt*16+quad*4+rr]
  float accl[2] = {0.f, 0.f};  // per-lane partial row sums (row i=c)

  // K/V staging: lane covers row w*16 + {0,8} + (lane>>3), phys chunk lane&7
  int slr = lane >> 3, slc = lane & 7;
  int ssw = (slc ^ slr) * 8;                // swizzled source elem offset
  const unsigned short* kp = kbase + (size_t)(s * kvlen + w * 16 + slr) * DH + ssw;
  const unsigned short* vp = vbase + (size_t)(w * 16 + slr) * NSEQ + s * kvlen + ssw;
  int sw0 = (quad ^ (c & 7)) * 8;           // ds_read swizzled chunk offsets
  int sw1 = sw0 ^ 32;

  int nIt = kvlen / 64;
  GLD16(kp,            &Kl[0][(w * 16)     * 64]);
  GLD16(kp + 8 * DH,   &Kl[0][(w * 16 + 8) * 64]);
  GLD16(vp,            &Vl[0][(w * 16)     * 64]);
  GLD16(vp + 8 * NSEQ, &Vl[0][(w * 16 + 8) * 64]);
  kp += 64 * DH; vp += 64;

  for (int it = 0; it < nIt; it++) {
    int cur = it & 1;
    __syncthreads();   // buf[cur] ready (vmcnt drained); prior reads done
    if (it + 1 < nIt) {
      int nb = cur ^ 1;
      GLD16(kp,            &Kl[nb][(w * 16)     * 64]);
      GLD16(kp + 8 * DH,   &Kl[nb][(w * 16 + 8) * 64]);
      GLD16(vp,            &Vl[nb][(w * 16)     * 64]);
      GLD16(vp + 8 * NSEQ, &Vl[nb][(w * 16 + 8) * 64]);
      kp += 64 * DH; vp += 64;
    }

    // QK^T -> S^T tiles (C-layout: z[rr] = S^T[j=16jt+quad*4+rr][i=c]),
    // exp2 + pack in-register -> B-operand frags of the K=16 PV MFMA.
    s16x4 pf[2][4];
#pragma unroll
    for (int jt = 0; jt < 4; jt++) {
      bf16x8 k0 = ldb(&Kl[cur][(jt * 16 + c) * 64 + sw0]);
      bf16x8 k1 = ldb(&Kl[cur][(jt * 16 + c) * 64 + sw1]);
      f32x4 zl = {}; zl = mm(k0, qlo0, zl); zl = mm(k1, qlo1, zl);
      f32x4 zh = {}; zh = mm(k0, qhi0, zh); zh = mm(k1, qhi1, zh);
      float a0 = exp2f(zl[0]), a1 = exp2f(zl[1]),
            a2 = exp2f(zl[2]), a3 = exp2f(zl[3]);
      accl[0] += (a0 + a1) + (a2 + a3);
      uint2 pl = { pack2(a0, a1), pack2(a2, a3) };
      pf[0][jt] = *(s16x4*)&pl;
      float b0 = exp2f(zh[0]), b1 = exp2f(zh[1]),
            b2 = exp2f(zh[2]), b3 = exp2f(zh[3]);
      accl[1] += (b0 + b1) + (b2 + b3);
      uint2 ph = { pack2(b0, b1), pack2(b2, b3) };
      pf[1][jt] = *(s16x4*)&ph;
    }
    // PV: O^T[d][i] += V^T[d][j] * P^T[j][i]  (16x16x16, A from Vl b64)
#pragma unroll
    for (int dt = 0; dt < 4; dt++) {
      int row = dt * 16 + c;
      int rx = row & 7;
#pragma unroll
      for (int jt = 0; jt < 4; jt++) {
        int cj = jt * 2 + (quad >> 1);
        s16x4 a = *(const s16x4*)&Vl[cur][row * 64 + (((cj ^ rx) * 8) | ((quad & 1) * 4))];
        acc[0][dt] = mm16(a, pf[0][jt], acc[0][dt]);
        acc[1][dt] = mm16(a, pf[1][jt], acc[1][dt]);
      }
    }
  }

  // finish row sums: reduce across quads (row i=c fixed per lane)
  accl[0] += __shfl_xor(accl[0], 16); accl[0] += __shfl_xor(accl[0], 32);
  accl[1] += __shfl_xor(accl[1], 16); accl[1] += __shfl_xor(accl[1], 32);

  size_t rb = ((size_t)(b * NH + h) * S + s) * NSEQ + i0 + w * 32;
  if (quad == 0) {
    lpart[rb + c]      = accl[0];
    lpart[rb + 16 + c] = accl[1];
  }
#pragma unroll
  for (int dt = 0; dt < 4; dt++) {
    uint2 p0 = { pack2(acc[0][dt][0], acc[0][dt][1]),
                 pack2(acc[0][dt][2], acc[0][dt][3]) };
    *(uint2*)&opart[(rb + c) * 64 + dt * 16 + quad * 4] = p0;
    uint2 p1 = { pack2(acc[1][dt][0], acc[1][dt][1]),
                 pack2(acc[1][dt][2], acc[1][dt][3]) };
    *(uint2*)&opart[(rb + 16 + c) * 64 + dt * 16 + quad * 4] = p1;
  }
}

// ------ Kernel 3b: merge split-KV partials (plain sums) -> ao bf16 ----------
__global__ __launch_bounds__(256) void k_merge(
    const unsigned short* __restrict__ opart,
    const float* __restrict__ lpart,
    unsigned short* __restrict__ ao, int S) {
  int t = blockIdx.x * 256 + threadIdx.x;     // 131072 threads
  int row = t >> 2;                            // (b*NH+h)*NSEQ + i
  int dseg = (t & 3) * 16;
  int b = row >> 14, rem = row & 16383;
  int h = rem >> 12, i = rem & 4095;

  float l = 0.f;
  float o[16];
#pragma unroll
  for (int j = 0; j < 16; j++) o[j] = 0.f;
  for (int s = 0; s < S; s++) {
    size_t rb = ((size_t)(b * NH + h) * S + s) * NSEQ + i;
    l += lpart[rb];
    const unsigned short* p = opart + rb * 64 + dseg;
    u16x8 v0 = *(const u16x8*)p;
    u16x8 v1 = *(const u16x8*)(p + 8);
#pragma unroll
    for (int j = 0; j < 8; j++) {
      o[j]     += bf2f(v0[j]);
      o[8 + j] += bf2f(v1[j]);
    }
  }
  float inv = 1.f / l;
  unsigned short* dst = ao + ((size_t)b * NSEQ + i) * INNER + h * 64 + dseg;
  uint4 pk0 = { pack2(o[0] * inv, o[1] * inv),  pack2(o[2] * inv, o[3] * inv),
                pack2(o[4] * inv, o[5] * inv),  pack2(o[6] * inv, o[7] * inv) };
  uint4 pk1 = { pack2(o[8] * inv, o[9] * inv),  pack2(o[10] * inv, o[11] * inv),
                pack2(o[12] * inv, o[13] * inv),pack2(o[14] * inv, o[15] * inv) };
  *(uint4*)dst = pk0;
  *(uint4*)(dst + 8) = pk1;
}

// ------ Kernel 4: out-proj + residual, BK=128 (3 barriers total) ------------
__global__ __launch_bounds__(256) void k_out(const unsigned short* __restrict__ wob,
                                             const unsigned short* __restrict__ ao,
                                             const float* __restrict__ x,
                                             float* __restrict__ out) {
  int n0 = blockIdx.x * 64;
  int o0 = blockIdx.y * 64;
  int b  = blockIdx.z;
  __shared__ unsigned short Al[64 * 128];
  __shared__ unsigned short Bl[64 * 128];
  int t = threadIdx.x;
  int lane = t & 63, w = t >> 6;
  int c = lane & 15, quad = lane >> 4;
  int wm = w >> 1, wn = w & 1;
  f32x4 acc[2][2] = {};
  int lr = lane >> 4;
  int lchk = lane & 15;
  const unsigned short* apg = wob + (size_t)o0 * INNER;
  const unsigned short* bpg = ao + ((size_t)b * NSEQ + n0) * INNER;
  for (int kt = 0; kt < 2; kt++) {
    if (kt) __syncthreads();
#pragma unroll
    for (int q = 0; q < 4; q++) {
      int r = w * 16 + q * 4 + lr;
      int srcoff = r * INNER + kt * 128 + ((lchk ^ (r & 7)) * 8);
      GLD16(apg + srcoff, Al + (size_t)(w * 16 + q * 4) * 128);
      GLD16(bpg + srcoff, Bl + (size_t)(w * 16 + q * 4) * 128);
    }
    __syncthreads();
#pragma unroll
    for (int ks = 0; ks < 4; ks++) {
      int ra0 = wm * 32 + c, ra1 = ra0 + 16;
      int rb0 = wn * 32 + c, rb1 = rb0 + 16;
      bf16x8 a0 = ldb(&Al[ra0 * 128 + (((ks * 4 + quad) ^ (ra0 & 7)) * 8)]);
      bf16x8 a1 = ldb(&Al[ra1 * 128 + (((ks * 4 + quad) ^ (ra1 & 7)) * 8)]);
      bf16x8 b0 = ldb(&Bl[rb0 * 128 + (((ks * 4 + quad) ^ (rb0 & 7)) * 8)]);
      bf16x8 b1 = ldb(&Bl[rb1 * 128 + (((ks * 4 + quad) ^ (rb1 & 7)) * 8)]);
      acc[0][0] = mm(a0, b0, acc[0][0]);
      acc[0][1] = mm(a0, b1, acc[0][1]);
      acc[1][0] = mm(a1, b0, acc[1][0]);
      acc[1][1] = mm(a1, b1, acc[1][1]);
    }
  }
#pragma unroll
  for (int i = 0; i < 2; i++)
#pragma unroll
    for (int j = 0; j < 2; j++)
#pragma unroll
      for (int rr = 0; rr < 4; rr++) {
        int o = o0 + wm * 32 + i * 16 + quad * 4 + rr;
        int n = n0 + wn * 32 + j * 16 + c;
        size_t idx = ((size_t)b * CCH + o) * NSEQ + n;
        out[idx] = acc[i][j][rr] + x[idx];
      }
}

extern "C" void kernel_launch(void* const* d_in, const int* in_sizes, int n_in,
                              void* d_out, int out_size, void* d_ws, size_t ws_size,
                              hipStream_t stream) {
  const float* x     = (const float*)d_in[0];
  const float* gamma = (const float*)d_in[1];
  const float* wq    = (const float*)d_in[2];
  const float* wo    = (const float*)d_in[3];
  float* out = (float*)d_out;

  const size_t MB = 1u << 20;
  char* ws = (char*)d_ws;
  // ws layout:
  unsigned short* ao  = (unsigned short*)ws;                   // [0,4)  bf16 [B][N][256]
  unsigned short* xn  = (unsigned short*)(ws + 4 * MB);        // [4,8)  bf16 [B][N][256]
  unsigned short* qkv = (unsigned short*)(ws + 8 * MB);        // [8,20) bf16 [B][768][N] (v region used)
  unsigned short* wqb = (unsigned short*)(ws + 20 * MB);       // 384 KB
  unsigned short* wob = (unsigned short*)(ws + 20 * MB + 512 * 1024); // 128 KB
  unsigned short* qt  = (unsigned short*)(ws + 21 * MB);       // [21,25) bf16 [B][H][N][D]
  unsigned short* ktb = (unsigned short*)(ws + 25 * MB);       // [25,29) bf16 [B][H][N][D]
  unsigned short* opart = (unsigned short*)(ws + 29 * MB);     // S*B*H*N*64 bf16
  int S;
  if (ws_size >= 48 * MB) S = 4;
  else if (ws_size >= 40 * MB) S = 2;
  else S = 1;
  size_t opart_bytes = (size_t)S * BATCH * NH * NSEQ * DH * 2;
  float* lpart = (float*)(ws + 29 * MB + opart_bytes);
  int kvlen = NSEQ / S;

  k_lncvt<<<dim3(512),          256, 0, stream>>>(x, gamma, xn, wq, wo, wqb, wob);
  k_qkv  <<<dim3(64, 12, 2),    256, 0, stream>>>(wqb, xn, qkv, qt, ktb);
  k_attn <<<dim3(32, 4, 2 * S), 256, 0, stream>>>(qt, ktb, qkv, opart,
                                                  lpart, S, kvlen);
  k_merge<<<dim3(512),          256, 0, stream>>>(opart, lpart, ao, S);
  k_out  <<<dim3(64, 4, 2),     256, 0, stream>>>(wob, ao, x, out);
}